// Round 3
// baseline (49.848 us; speedup 1.0000x reference)
//
#include <hip/hip_runtime.h>
#include <math.h>

// Multitask loss (fused single pass):
//   loss = mean(bce(pb, tb))                       [B]
//        + mean(bce(pt, tt))                       [B,5]  (mean over 5B elems)
//        + mean(-log_softmax(ps)[i, ts[i]])        [B,16]
//        + mean((pb>0) ^ (pt[:,0]>0))
//        + mean((pb>0) ^ (argmax(ps)>0))
// bce(x,y) = max(x,0) - x*y + log1p(exp(-|x|))
//
// Fast intrinsics (__expf/__logf -> v_exp_f32/v_log_f32): tolerance is 0.117
// absmax on a ~5.8 scalar, so ~1e-6 relative error is fine.
//
// __launch_bounds__(256, 2): min 2 waves/EU -> VGPR cap 256. The bare
// (256) form capped VGPRs at 32 and spilled ~32 B/row to scratch
// (WRITE_SIZE was 66 MB vs 16 KB of real writes).

#define NBLOCKS 2048
#define NTHREADS 256

__device__ __forceinline__ float bce_term(float x, float y) {
    // max(x,0) - x*y + log1p(exp(-|x|)); log arg in (1,2] -> no cancellation
    return fmaxf(x, 0.0f) - x * y + __logf(1.0f + __expf(-fabsf(x)));
}

__global__ __launch_bounds__(NTHREADS, 2) void mtl_partial_kernel(
    const float* __restrict__ pb,   // [B]    y_pred_binary
    const float* __restrict__ pt,   // [B,5]  y_pred_type
    const float* __restrict__ ps,   // [B,16] y_pred_source
    const float* __restrict__ tb,   // [B]    y_true_binary
    const float* __restrict__ tt,   // [B,5]  y_true_type
    const int*   __restrict__ ts,   // [B]    y_true_source
    double* __restrict__ partial,   // [NBLOCKS]
    int B)
{
    const int tid = blockIdx.x * NTHREADS + threadIdx.x;
    const int stride = NBLOCKS * NTHREADS;

    float acc = 0.0f;  // ~4 rows (~6 each) + ~20 BCE elems (~0.7) : f32 fine

    // ---- loop 1: per-row work (tasks A, C, XOR terms) ----
    for (int i = tid; i < B; i += stride) {
        const float xb = pb[i];
        const float yb = tb[i];
        const int   t  = ts[i];
        const float t0 = pt[(size_t)i * 5];  // only col 0 needed here

        float c = fmaxf(xb, 0.0f) - xb * yb + __logf(1.0f + __expf(-fabsf(xb)));

        // 16-way CE over log_softmax
        float xs[16];  // static indexing only
        const float4* ps4 = reinterpret_cast<const float4*>(ps + (size_t)i * 16);
        #pragma unroll
        for (int q = 0; q < 4; ++q) {
            const float4 v = ps4[q];
            xs[q * 4 + 0] = v.x;
            xs[q * 4 + 1] = v.y;
            xs[q * 4 + 2] = v.z;
            xs[q * 4 + 3] = v.w;
        }
        // argmax>0  <=>  max(xs[1..15]) > xs[0] (strict, first-occurrence ties)
        float m15 = xs[1];
        #pragma unroll
        for (int j = 2; j < 16; ++j) m15 = fmaxf(m15, xs[j]);
        const float m = fmaxf(xs[0], m15);

        float se = 0.0f;
        float xt = 0.0f;  // xs[t] via unrolled cndmask chain (no scratch)
        #pragma unroll
        for (int j = 0; j < 16; ++j) {
            se += __expf(xs[j] - m);
            xt = (j == t) ? xs[j] : xt;
        }
        c += m + __logf(se) - xt;  // -logp[t]

        // consistency XOR terms
        const bool bc = xb > 0.0f;
        c += (bc != (t0 > 0.0f)) ? 1.0f : 0.0f;
        c += (bc != (m15 > xs[0])) ? 1.0f : 0.0f;

        acc += c;
    }

    // ---- loop 2: task B BCE, vectorized float4 over contiguous [B*5] ----
    {
        const int n  = B * 5;
        const int n4 = n >> 2;  // exact for B = 2^21; tail handled below
        const float4* pt4 = reinterpret_cast<const float4*>(pt);
        const float4* tt4 = reinterpret_cast<const float4*>(tt);
        float accB = 0.0f;
        for (int i = tid; i < n4; i += stride) {
            const float4 x = pt4[i];
            const float4 y = tt4[i];
            accB += bce_term(x.x, y.x);
            accB += bce_term(x.y, y.y);
            accB += bce_term(x.z, y.z);
            accB += bce_term(x.w, y.w);
        }
        // scalar tail (0..3 elems), grid-stride
        for (int i = (n4 << 2) + tid; i < n; i += stride)
            accB += bce_term(pt[i], tt[i]);
        acc += accB * 0.2f;
    }

    // ---- block reduction (wave shfl in f32, then cross-wave via LDS) ----
    float a = acc;
    #pragma unroll
    for (int off = 32; off > 0; off >>= 1)
        a += __shfl_down(a, off, 64);

    __shared__ double smem[NTHREADS / 64];
    const int lane = threadIdx.x & 63;
    const int wave = threadIdx.x >> 6;
    if (lane == 0) smem[wave] = (double)a;
    __syncthreads();
    if (threadIdx.x == 0) {
        double s = 0.0;
        #pragma unroll
        for (int w = 0; w < NTHREADS / 64; ++w) s += smem[w];
        partial[blockIdx.x] = s;
    }
}

__global__ __launch_bounds__(NTHREADS) void mtl_final_kernel(
    const double* __restrict__ partial, float* __restrict__ out, int nblocks, int B)
{
    double acc = 0.0;
    for (int i = threadIdx.x; i < nblocks; i += NTHREADS)
        acc += partial[i];
    #pragma unroll
    for (int off = 32; off > 0; off >>= 1)
        acc += __shfl_down(acc, off, 64);
    __shared__ double smem[NTHREADS / 64];
    const int lane = threadIdx.x & 63;
    const int wave = threadIdx.x >> 6;
    if (lane == 0) smem[wave] = acc;
    __syncthreads();
    if (threadIdx.x == 0) {
        double s = 0.0;
        #pragma unroll
        for (int w = 0; w < NTHREADS / 64; ++w) s += smem[w];
        out[0] = (float)(s / (double)B);
    }
}

extern "C" void kernel_launch(void* const* d_in, const int* in_sizes, int n_in,
                              void* d_out, int out_size, void* d_ws, size_t ws_size,
                              hipStream_t stream) {
    const float* pb = (const float*)d_in[0];
    const float* pt = (const float*)d_in[1];
    const float* ps = (const float*)d_in[2];
    const float* tb = (const float*)d_in[3];
    const float* tt = (const float*)d_in[4];
    const int*   ts = (const int*)d_in[5];
    float* out = (float*)d_out;
    const int B = in_sizes[0];

    double* partial = (double*)d_ws;  // NBLOCKS doubles = 16 KiB

    mtl_partial_kernel<<<NBLOCKS, NTHREADS, 0, stream>>>(pb, pt, ps, tb, tt, ts, partial, B);
    mtl_final_kernel<<<1, NTHREADS, 0, stream>>>(partial, out, NBLOCKS, B);
}

// Round 4
// 49.330 us; speedup vs baseline: 1.0105x; 1.0105x over previous
//
#include <hip/hip_runtime.h>
#include <math.h>

// Multitask loss (fused single pass, 4 rows/thread, all-dwordx4 loads):
//   loss = mean(bce(pb, tb))                       [B]
//        + mean(bce(pt, tt))                       [B,5]  (mean over 5B elems)
//        + mean(-log_softmax(ps)[i, ts[i]])        [B,16]
//        + mean((pb>0) ^ (pt[:,0]>0))
//        + mean((pb>0) ^ (argmax(ps)>0))
// bce(x,y) = max(x,0) - x*y + log1p(exp(-|x|))
//
// Fast intrinsics (__expf/__logf): tolerance 0.117 absmax on a ~5.8 scalar.
// 4 rows/thread makes every global load an aligned dwordx4:
//   pb,tb: float4; ts: int4; pt,tt: 5x float4 (20 floats, base 80k B is
//   16B-aligned); ps: 16x float4. 464 B/thread, one pass.

#define NTHREADS 256
#define ROWS_PER_THREAD 4

__device__ __forceinline__ float bce_term(float x, float y) {
    // max(x,0) - x*y + log1p(exp(-|x|)); log arg in (1,2] -> no cancellation
    return fmaxf(x, 0.0f) - x * y + __logf(1.0f + __expf(-fabsf(x)));
}

__device__ __forceinline__ float row_ACX(const float* __restrict__ ps,
                                         float xb, float yb, int t, float t0,
                                         size_t row) {
    // task A BCE + task C CE + two XOR terms for one row
    float c = fmaxf(xb, 0.0f) - xb * yb + __logf(1.0f + __expf(-fabsf(xb)));

    float xs[16];  // static indexing only (fully unrolled below)
    const float4* ps4 = reinterpret_cast<const float4*>(ps + row * 16);
    #pragma unroll
    for (int q = 0; q < 4; ++q) {
        const float4 v = ps4[q];
        xs[q * 4 + 0] = v.x;
        xs[q * 4 + 1] = v.y;
        xs[q * 4 + 2] = v.z;
        xs[q * 4 + 3] = v.w;
    }
    // argmax>0  <=>  max(xs[1..15]) > xs[0] (strict, first-occurrence ties)
    float m15 = xs[1];
    #pragma unroll
    for (int j = 2; j < 16; ++j) m15 = fmaxf(m15, xs[j]);
    const float m = fmaxf(xs[0], m15);

    float se = 0.0f;
    float xt = 0.0f;  // xs[t] via unrolled cndmask chain
    #pragma unroll
    for (int j = 0; j < 16; ++j) {
        se += __expf(xs[j] - m);
        xt = (j == t) ? xs[j] : xt;
    }
    c += m + __logf(se) - xt;  // -logp[t]

    const bool bc = xb > 0.0f;
    c += (bc != (t0 > 0.0f)) ? 1.0f : 0.0f;
    c += (bc != (m15 > xs[0])) ? 1.0f : 0.0f;
    return c;
}

__global__ __launch_bounds__(NTHREADS) void mtl_partial_kernel(
    const float* __restrict__ pb,   // [B]    y_pred_binary
    const float* __restrict__ pt,   // [B,5]  y_pred_type
    const float* __restrict__ ps,   // [B,16] y_pred_source
    const float* __restrict__ tb,   // [B]    y_true_binary
    const float* __restrict__ tt,   // [B,5]  y_true_type
    const int*   __restrict__ ts,   // [B]    y_true_source
    double* __restrict__ partial,   // [gridDim.x]
    int B)
{
    const int tid = blockIdx.x * NTHREADS + threadIdx.x;
    const int i0  = tid * ROWS_PER_THREAD;

    float acc = 0.0f;  // 4 rows (~8 max each) + 20 BCE elems: f32 exact enough

    if (i0 + ROWS_PER_THREAD <= B) {
        // ---- fully vectorized path: every load is an aligned dwordx4 ----
        const float4 pb4 = *reinterpret_cast<const float4*>(pb + i0);
        const float4 tb4 = *reinterpret_cast<const float4*>(tb + i0);
        const int4   ts4 = *reinterpret_cast<const int4*>(ts + i0);

        // pt/tt group: 20 floats starting at float 5*i0 (byte 20*i0, i0%4==0
        // -> 16B aligned)
        float ptv[20], ttv[20];
        const float4* p4 = reinterpret_cast<const float4*>(pt + (size_t)i0 * 5);
        const float4* t4 = reinterpret_cast<const float4*>(tt + (size_t)i0 * 5);
        #pragma unroll
        for (int q = 0; q < 5; ++q) {
            const float4 a = p4[q];
            ptv[q * 4 + 0] = a.x; ptv[q * 4 + 1] = a.y;
            ptv[q * 4 + 2] = a.z; ptv[q * 4 + 3] = a.w;
            const float4 b = t4[q];
            ttv[q * 4 + 0] = b.x; ttv[q * 4 + 1] = b.y;
            ttv[q * 4 + 2] = b.z; ttv[q * 4 + 3] = b.w;
        }

        // task B: BCE over all 20 elems (weight 1/5 of per-row mean)
        float st = 0.0f;
        #pragma unroll
        for (int j = 0; j < 20; ++j) st += bce_term(ptv[j], ttv[j]);
        acc += st * 0.2f;

        const float xbv[4] = { pb4.x, pb4.y, pb4.z, pb4.w };
        const float ybv[4] = { tb4.x, tb4.y, tb4.z, tb4.w };
        const int   tv[4]  = { ts4.x, ts4.y, ts4.z, ts4.w };
        #pragma unroll
        for (int r = 0; r < 4; ++r)
            acc += row_ACX(ps, xbv[r], ybv[r], tv[r], ptv[r * 5],
                           (size_t)(i0 + r));
    } else {
        // ---- scalar tail (only if B % 4 != 0; B = 2^21 -> unused) ----
        for (int i = i0; i < B; ++i) {
            const float* ptr = pt + (size_t)i * 5;
            const float* ttr = tt + (size_t)i * 5;
            float st = 0.0f;
            #pragma unroll
            for (int j = 0; j < 5; ++j) st += bce_term(ptr[j], ttr[j]);
            acc += st * 0.2f;
            acc += row_ACX(ps, pb[i], tb[i], ts[i], ptr[0], (size_t)i);
        }
    }

    // ---- block reduction (wave shfl in f32, then cross-wave via LDS) ----
    float a = acc;
    #pragma unroll
    for (int off = 32; off > 0; off >>= 1)
        a += __shfl_down(a, off, 64);

    __shared__ double smem[NTHREADS / 64];
    const int lane = threadIdx.x & 63;
    const int wave = threadIdx.x >> 6;
    if (lane == 0) smem[wave] = (double)a;
    __syncthreads();
    if (threadIdx.x == 0) {
        double s = 0.0;
        #pragma unroll
        for (int w = 0; w < NTHREADS / 64; ++w) s += smem[w];
        partial[blockIdx.x] = s;
    }
}

__global__ __launch_bounds__(NTHREADS) void mtl_final_kernel(
    const double* __restrict__ partial, float* __restrict__ out, int nblocks, int B)
{
    double acc = 0.0;
    for (int i = threadIdx.x; i < nblocks; i += NTHREADS)
        acc += partial[i];
    #pragma unroll
    for (int off = 32; off > 0; off >>= 1)
        acc += __shfl_down(acc, off, 64);
    __shared__ double smem[NTHREADS / 64];
    const int lane = threadIdx.x & 63;
    const int wave = threadIdx.x >> 6;
    if (lane == 0) smem[wave] = acc;
    __syncthreads();
    if (threadIdx.x == 0) {
        double s = 0.0;
        #pragma unroll
        for (int w = 0; w < NTHREADS / 64; ++w) s += smem[w];
        out[0] = (float)(s / (double)B);
    }
}

extern "C" void kernel_launch(void* const* d_in, const int* in_sizes, int n_in,
                              void* d_out, int out_size, void* d_ws, size_t ws_size,
                              hipStream_t stream) {
    const float* pb = (const float*)d_in[0];
    const float* pt = (const float*)d_in[1];
    const float* ps = (const float*)d_in[2];
    const float* tb = (const float*)d_in[3];
    const float* tt = (const float*)d_in[4];
    const int*   ts = (const int*)d_in[5];
    float* out = (float*)d_out;
    const int B = in_sizes[0];

    const int rpb  = NTHREADS * ROWS_PER_THREAD;
    const int grid = (B + rpb - 1) / rpb;   // 2048 for B = 2^21

    double* partial = (double*)d_ws;  // grid doubles (16 KiB at 2048)

    mtl_partial_kernel<<<grid, NTHREADS, 0, stream>>>(pb, pt, ps, tb, tt, ts, partial, B);
    mtl_final_kernel<<<1, NTHREADS, 0, stream>>>(partial, out, grid, B);
}